// Round 6
// baseline (175.022 us; speedup 1.0000x reference)
//
#include <hip/hip_runtime.h>
#include <math.h>

// ---- compile-time physical constants (mirror the Python reference) ----
namespace k {
constexpr double dA     = 0.129907 + 0.095724;       // L_X + L_Y
constexpr double dR     = 4.0 * 0.0254;              // wheel radius
constexpr double dI     = 6.0;                       // inertia (== mass)
constexpr double dMOI   = 6.0 * (12.0 * 0.0254) * (12.0 * 0.0254) / 6.0;
constexpr float T_STALL   = (float)(5.4 / 100.0);
constexpr float INV_WFREE = (float)(1.0 / (1620.0 / 60.0 * 2.0 * 3.14159265358979323846));
constexpr float A         = (float)dA;
constexpr float INV_R     = (float)(1.0 / dR);
constexpr float INV_RI    = (float)(1.0 / (dR * dI));    // WT2LA rows 0,1 scale
constexpr float A_RMOI    = (float)(dA / (dR * dMOI));   // WT2LA row 2 scale
}

typedef float f32x4 __attribute__((ext_vector_type(4)));
typedef float f32x2 __attribute__((ext_vector_type(2)));

__device__ __forceinline__ float wheel_torque(float w, float m) {
    float p = m * w;
    // jnp.sign semantics: sign(0)=0 -> is_same_direction = 0.5
    float sgn = (float)(p > 0.0f) - (float)(p < 0.0f);
    float isd = 0.5f * (sgn + 1.0f);
    return k::T_STALL * (1.0f - fabsf(w) * isd * k::INV_WFREE) * m;
}

// ---------------------------------------------------------------------------
// R6 = R4 revert: best-measured variant (<=55.5 us kernel, harness 175.0).
//
// Session evidence (5 structurally distinct kernels, 55.5-61 us):
//   R0 LDS+2 barriers, 49% occ ......... 57.7 us
//   R2 barrier-free LDS, ~100% occ ..... ~56   (occupancy: neutral)
//   R3 persistent dbuf pipeline ........ 57.4-59.2 (pipelining: neutral)
//   R4 direct, no LDS, native trig ..... <=55.5 (BEST)
//   R5 MLP-4, 4 streams ................ 60.3  (latency hiding: falsified)
// No counter saturates from inside the kernel (VALU<=19%, visible HBM 31%).
// The window is DRAM-saturated by the harness's 2x384 MB poison-fill
// writeback draining concurrently: ~141 MB visible + ~300 MB drain over
// ~56 us ~= 8 TB/s ~= DRAM peak -> kernel time invariant to structure.
//
// This kernel is the traffic-minimal correct implementation:
//   - reference never reads state[...,0:2] -> one 16 B load @ 24i+8
//   - one 16 B + one 8 B store cover the full 24 B output row
//   - native __sinf/__cosf (tolerance 7.8e-3 >> native error ~1e-6)
//   - no LDS, no barriers, 20 VGPR, one element per thread
// ---------------------------------------------------------------------------
__global__ __launch_bounds__(256) void mecanum_direct_kernel(
    const float* __restrict__ state,
    const float* __restrict__ cd,
    float* __restrict__ out,
    int n) {
    int i = blockIdx.x * 256 + threadIdx.x;
    if (i >= n) return;

    // batch-uniform motor duty: CD2MD @ control_duty (scalar s_load path)
    float u0 = cd[0], u1 = cd[1], u2 = cd[2];
    float m0 = u0 - u1 - u2;
    float m1 = u0 + u1 + u2;
    float m2 = u0 + u1 - u2;
    float m3 = u0 - u1 + u2;

    // ---- load [theta, v0, v1, v2]: 16 B @ byte 24*i+8 (8-aligned) ----
    f32x4 tv;
    __builtin_memcpy(&tv, state + 6 * i + 2, 16);
    float theta = tv.x, v0 = tv.y, v1 = tv.z, v2 = tv.w;

    float s = __sinf(theta);
    float c = __cosf(theta);

    // a2l = rot(cos(-t), sin(-t)) -> [[c, s, 0], [-s, c, 0], [0,0,1]]
    float lv0 = c * v0 + s * v1;
    float lv1 = c * v1 - s * v0;

    // wheel_vel = LV2WV @ local_vel
    float al2 = k::A * v2;
    float w0 = (lv0 - lv1 - al2) * k::INV_R;
    float w1 = (lv0 + lv1 + al2) * k::INV_R;
    float w2 = (lv0 + lv1 - al2) * k::INV_R;
    float w3 = (lv0 - lv1 + al2) * k::INV_R;

    float t0 = wheel_torque(w0, m0);
    float t1 = wheel_torque(w1, m1);
    float t2 = wheel_torque(w2, m2);
    float t3 = wheel_torque(w3, m3);

    // local_accel = WT2LA @ torque
    float la0 = (t0 + t1 + t2 + t3) * k::INV_RI;
    float la1 = (-t0 + t1 + t2 - t3) * k::INV_RI;
    float la2 = (-t0 + t1 - t2 + t3) * k::A_RMOI;

    // l2a = rot(cos(t), sin(t)) -> [[c,-s,0],[s,c,0],[0,0,1]]
    float aa0 = c * la0 - s * la1;
    float aa1 = s * la0 + c * la1;

    // ---- store [v0,v1,v2,aa0] @ 24*i (16 B) + [aa1,la2] @ 24*i+16 (8 B) ----
    f32x4 o1; o1.x = v0; o1.y = v1; o1.z = v2; o1.w = aa0;
    __builtin_memcpy(out + 6 * i, &o1, 16);
    f32x2 o2; o2.x = aa1; o2.y = la2;
    __builtin_memcpy(out + 6 * i + 4, &o2, 8);
}

extern "C" void kernel_launch(void* const* d_in, const int* in_sizes, int n_in,
                              void* d_out, int out_size, void* d_ws, size_t ws_size,
                              hipStream_t stream) {
    // inputs: d_in[0] = t (1, unused), d_in[1] = state (BATCH*6), d_in[2] = control_duty (3)
    const float* state = (const float*)d_in[1];
    const float* cd    = (const float*)d_in[2];
    float* out         = (float*)d_out;

    int n = in_sizes[1] / 6;        // batch size

    if (n > 0) {
        int grid = (n + 255) / 256;
        mecanum_direct_kernel<<<grid, 256, 0, stream>>>(state, cd, out, n);
    }
}